// Round 1
// baseline (1433.469 us; speedup 1.0000x reference)
//
#include <hip/hip_runtime.h>
#include <stdint.h>

// genericPINN: fused RFF-MLP forward + 3 JVPs, f16 MFMA, activations LDS-resident.
// Block = 512 thr (8 waves), 24 samples (96 stream-rows), full-N accumulation in regs,
// weights streamed as pre-swizzled f16 image via global_load_lds (dbuf 2x32KB).

#define B_SZ   65536
#define NN     512
#define NL     8
#define SPB    24            // samples per block
#define MROWS  96            // 4 * SPB  (stream-rows)
#define MT     6             // 96/16 M-tiles
#define NTW    4             // N-tiles of 16 per wave (64 cols/wave * 8 waves = 512)
#define NKB    16            // K blocks per layer (512/32)
#define KB_BYTES 32768       // one staged W block: 512 n-rows * 64 B
#define LDS_A  (MROWS*1024)  // 98304: A, row-major 1024B rows, xor-swizzled
#define LDS_TOTAL (LDS_A + 2*KB_BYTES)   // 163840 == full 160 KiB

typedef _Float16 f16x8 __attribute__((ext_vector_type(8)));
typedef float    f32x4 __attribute__((ext_vector_type(4)));

__device__ __forceinline__ uint16_t f2h_bits(float f) {
  union { _Float16 h; uint16_t u; } v; v.h = (_Float16)f; return v.u;
}
__device__ __forceinline__ float h2f(uint16_t b) {
  union { uint16_t u; _Float16 h; } v; v.u = b; return (float)v.h;
}

// ---- prep: Ws (L,512,512) fp32 -> f16 image, [l][kb][n][swizzled 4x16B k-frags] ----
// image fragment content: W[l][kb*32 + kq*8 + e][n], e=0..7 -> 16B, placed at
// n*64 + 16*((kq + (n>>1)) & 3)  (swizzle baked in so global_load_lds streams linearly)
__global__ __launch_bounds__(512) void prep_weights(const float* __restrict__ Ws,
                                                    uint16_t* __restrict__ img) {
  const int n  = threadIdx.x;
  const int kb = blockIdx.x & 15;
  const int l  = blockIdx.x >> 4;
  const float* src = Ws + ((size_t)l << 18) + n;          // + k*512 below
  char* dstbase = (char*)img + (((size_t)(l*16 + kb)) << 15) + (size_t)n * 64;
  #pragma unroll
  for (int kq = 0; kq < 4; ++kq) {
    uint16_t h[8];
    #pragma unroll
    for (int e = 0; e < 8; ++e) {
      int k = kb*32 + kq*8 + e;
      h[e] = f2h_bits(src[(size_t)k * 512]);              // coalesced across n
    }
    uint4 pk;
    pk.x = (uint32_t)h[0] | ((uint32_t)h[1] << 16);
    pk.y = (uint32_t)h[2] | ((uint32_t)h[3] << 16);
    pk.z = (uint32_t)h[4] | ((uint32_t)h[5] << 16);
    pk.w = (uint32_t)h[6] | ((uint32_t)h[7] << 16);
    *(uint4*)(dstbase + 16 * ((kq + (n >> 1)) & 3)) = pk;
  }
}

__global__ __launch_bounds__(512, 2) void pinn_fused(
    const float* __restrict__ inputs, const float* __restrict__ Brff,
    const float* __restrict__ bs, const float* __restrict__ alphas,
    const float* __restrict__ Wf, const float* __restrict__ scl,
    const uint16_t* __restrict__ wimg, float* __restrict__ out)
{
  extern __shared__ char smem[];
  char* wbuf0 = smem + LDS_A;
  char* wbuf1 = smem + LDS_A + KB_BYTES;

  const int tid  = threadIdx.x;
  const int lane = tid & 63;
  const int wv   = tid >> 6;       // wave 0..7
  const int i16  = lane & 15;
  const int q    = lane >> 4;      // quad
  const int sbase = blockIdx.x * SPB;

  // ---- stage B_rff (4x256 fp32 = 4KB) into weight-buffer area (free now) ----
  float* brff = (float*)wbuf0;
  brff[tid]       = Brff[tid];
  brff[tid + 512] = Brff[tid + 512];
  __syncthreads();

  // ---- layer 0: A0[m][k], m = 4*sample_local + stream, k = feature ----
  // u0 = [sin z, cos z];  du0_c = [cos z * B_c, -sin z * B_c],  z = x @ B_rff
  {
    const int k = tid;                 // this thread owns column k for all rows
    const int col = k & 255;
    const bool iscos = (k >= 256);
    const float b0 = brff[col], b1 = brff[256 + col], b2 = brff[512 + col], b3 = brff[768 + col];
    for (int m = 0; m < MROWS; ++m) {
      int s = sbase + (m >> 2); if (s >= B_SZ) s = B_SZ - 1;   // clamp tail block
      const int stream = m & 3;                                 // wave-uniform
      const float* x = inputs + (size_t)s * 4;                  // uniform -> s_load
      float z = x[0]*b0 + x[1]*b1 + x[2]*b2 + x[3]*b3;
      float szn = __sinf(z), czn = __cosf(z);
      float val;
      if (stream == 0) val = iscos ? czn : szn;
      else {
        float bc = (stream == 1) ? b1 : (stream == 2 ? b2 : b3);
        val = iscos ? (-szn * bc) : (czn * bc);
      }
      *(uint16_t*)(smem + m*1024 + ((2*k) ^ ((m & 7) * 16))) = f2h_bits(val);
    }
  }
  __syncthreads();

  // ---- stage helper: 32KB image block, 8 waves x 4 x (64 lanes x 16B) ----
  auto stage = [&](int g, char* buf) {
    const char* src = (const char*)wimg + ((size_t)g << 15) + (size_t)(wv*4) * 1024 + (size_t)lane * 16;
    char* dst = buf + (wv*4) * 1024;
    #pragma unroll
    for (int it = 0; it < 4; ++it) {
      __builtin_amdgcn_global_load_lds(
          (const __attribute__((address_space(1))) void*)(src + it*1024),
          (__attribute__((address_space(3))) void*)(dst + it*1024),
          16, 0, 0);
    }
  };

  stage(0, wbuf0);
  __syncthreads();   // drains stage(0)

  f32x4 acc[MT][NTW];

  for (int l = 0; l < NL; ++l) {
    const f32x4 zz = {0.f, 0.f, 0.f, 0.f};
    #pragma unroll
    for (int a = 0; a < MT; ++a)
      #pragma unroll
      for (int b = 0; b < NTW; ++b)
        acc[a][b] = zz;

    for (int kb = 0; kb < NKB; ++kb) {
      const int g = l*NKB + kb;
      char* cur = (g & 1) ? wbuf1 : wbuf0;
      if (g + 1 < NL*NKB) stage(g + 1, (g & 1) ? wbuf0 : wbuf1);

      // A-frags: A[m=i16][k = kb*32 + q*8 + j]  (xor-swizzled rows)
      f16x8 af[MT];
      #pragma unroll
      for (int Mt = 0; Mt < MT; ++Mt) {
        const int m = Mt*16 + i16;
        af[Mt] = *(const f16x8*)(smem + m*1024 + ((kb*64 + q*16) ^ ((i16 & 7) * 16)));
      }
      // B-frags: W[k = kb*32 + q*8 + j][n = wv*64 + Nt*16 + i16] from swizzled image
      f16x8 bfr[NTW];
      #pragma unroll
      for (int Nt = 0; Nt < NTW; ++Nt) {
        const int nc = wv*64 + Nt*16 + i16;
        bfr[Nt] = *(const f16x8*)(cur + nc*64 + 16 * ((q + (nc >> 1)) & 3));
      }
      #pragma unroll
      for (int Mt = 0; Mt < MT; ++Mt)
        #pragma unroll
        for (int Nt = 0; Nt < NTW; ++Nt)
          acc[Mt][Nt] = __builtin_amdgcn_mfma_f32_16x16x32_f16(af[Mt], bfr[Nt], acc[Mt][Nt], 0, 0, 0);
      __syncthreads();   // buffer rotate + drain prefetch
    }

    // ---- epilogue: h=(1+a)(dot+b); u'=sin h; du'=(1+a)cos(h)*dot_t ; overwrite A ----
    // C/D layout: col = i16 (-> neuron nc), row = q*4 + r (-> stream r, lane-local!)
    const float opa = 1.0f + alphas[l];
    #pragma unroll
    for (int Nt = 0; Nt < NTW; ++Nt) {
      const int nc = wv*64 + Nt*16 + i16;
      const float bias = bs[l*NN + nc];
      #pragma unroll
      for (int Mt = 0; Mt < MT; ++Mt) {
        f32x4 c = acc[Mt][Nt];
        float h  = opa * (c[0] + bias);
        float un = __sinf(h);
        float fc = opa * __cosf(h);
        float vv[4] = { un, fc*c[1], fc*c[2], fc*c[3] };
        const int mb = Mt*16 + q*4;
        #pragma unroll
        for (int r = 0; r < 4; ++r) {
          const int m = mb + r;
          *(uint16_t*)(smem + m*1024 + ((2*nc) ^ ((m & 7) * 16))) = f2h_bits(vv[r]);
        }
      }
    }
    __syncthreads();
  }

  // ---- final projection: dP[m][o] = sum_k A[m][k]*Wf[k][o] * scale[o] ----
  float* dp = (float*)wbuf0;        // 96x4 fp32 (weights no longer needed)
  const float4 sc4 = *(const float4*)scl;
  for (int rr = 0; rr < MROWS/8; ++rr) {     // 12 rows per wave
    const int m = wv * 12 + rr;
    float p0 = 0.f, p1 = 0.f, p2 = 0.f, p3 = 0.f;
    #pragma unroll
    for (int j = 0; j < 8; ++j) {
      const int k = lane + j*64;
      float a = h2f(*(const uint16_t*)(smem + m*1024 + ((2*k) ^ ((m & 7) * 16))));
      float4 wf = ((const float4*)Wf)[k];
      p0 += a*wf.x; p1 += a*wf.y; p2 += a*wf.z; p3 += a*wf.w;
    }
    #pragma unroll
    for (int d = 1; d < 64; d <<= 1) {
      p0 += __shfl_xor(p0, d, 64);
      p1 += __shfl_xor(p1, d, 64);
      p2 += __shfl_xor(p2, d, 64);
      p3 += __shfl_xor(p3, d, 64);
    }
    if (lane == 0) {
      float4* o = (float4*)(dp + m*4);
      *o = make_float4(p0*sc4.x, p1*sc4.y, p2*sc4.z, p3*sc4.w);
    }
  }
  __syncthreads();

  // rows 4s+1=dPdz, 4s+2=dPdx, 4s+3=dPdy
  // u = dPdy[2]-dPdz[1]+dPdx[3]; v = dPdz[0]-dPdx[2]+dPdy[3]; w = dPdx[1]-dPdy[0]+dPdz[3]
  if (tid < SPB*3) {
    const int sl = tid / 3, c = tid - sl*3;
    const int s = sbase + sl;
    if (s < B_SZ) {
      const float* d1 = dp + (sl*4 + 1)*4;
      const float* d2 = dp + (sl*4 + 2)*4;
      const float* d3 = dp + (sl*4 + 3)*4;
      float val;
      if (c == 0)      val = d3[2] - d1[1] + d2[3];
      else if (c == 1) val = d1[0] - d2[2] + d3[3];
      else             val = d2[1] - d3[0] + d1[3];
      out[(size_t)s*3 + c] = val;
    }
  }
}

extern "C" void kernel_launch(void* const* d_in, const int* in_sizes, int n_in,
                              void* d_out, int out_size, void* d_ws, size_t ws_size,
                              hipStream_t stream) {
  const float* inputs = (const float*)d_in[0];
  const float* Brff   = (const float*)d_in[1];
  const float* Ws     = (const float*)d_in[2];
  const float* bsp    = (const float*)d_in[3];
  const float* alph   = (const float*)d_in[4];
  const float* Wfp    = (const float*)d_in[5];
  const float* sclp   = (const float*)d_in[6];
  uint16_t* wimg = (uint16_t*)d_ws;           // needs 4 MiB workspace

  prep_weights<<<NL*NKB/2 * 2 /*=128*/, 512, 0, stream>>>(Ws, wimg);
  const int nblocks = (B_SZ + SPB - 1) / SPB; // 2731
  pinn_fused<<<nblocks, 512, LDS_TOTAL, stream>>>(inputs, Brff, bsp, alph, Wfp, sclp,
                                                  wimg, (float*)d_out);
}